// Round 4
// baseline (229.926 us; speedup 1.0000x reference)
//
#include <hip/hip_runtime.h>

namespace {

constexpr int BB = 64;
constexpr int DDIM = 196608;          // 3*256*256
constexpr float T_SCALE = 0.99f;      // 1 - 1/MAX_TIMESTEPS

// ws layout (floats). Per-block partials in bigp mirror ws offsets for idx<NRED.
constexpr int WS_ZD   = 0;            // 64*64  ZD[i][j] = z_i . d_j
constexpr int WS_DD   = 4096;         // 64*64  DD[i][j] = d_i . d_j
constexpr int WS_Z2   = 8192;         // 64     |z_i|^2
constexpr int WS_ELEM = 8256;         // 1      elementwise loss total
constexpr int NRED    = 8257;
constexpr int WS_U2   = 8320;         // 64 per-row sum(u^2)
constexpr int WS_BIGP = 8384;
constexpr int PSTRIDE = 8272;         // per-block stride (16B-aligned)

__global__ void k_init(float* __restrict__ ws) {
  int idx = blockIdx.x * 256 + threadIdx.x;
  if (idx < NRED) ws[idx] = 0.0f;
}

// ---------------------------------------------------------------------------
// k_main: raw-stream Grams + z2 row sums + wave-specialized elementwise loss.
//   ZD[i][j] = sum_k z_i[k] d_j[k],  DD[i][j] = sum_k d_i[k] d_j[k]
//   z2[i] = |z_i|^2
//   elem  = sum 0.5[(pm-fc)^2 + exp(plv)*plv - fc^2],  fc = d-z
// Block = 320 threads: waves 0-3 gram engine (ZD: waves 0,1 / DD: waves 2,3,
// k-halves), wave 4 elem engine over the block's own k-chunk (L2-hot d,z).
// LDS tiles k-major, quad XOR swizzle: word(k,r)=k*64+((r>>2)^(k&15))*4+(r&3).
// Gram staging: register prefetch (8 float4) of next subtile before GEMM.
// ---------------------------------------------------------------------------
template <int SUBT, bool ATOMIC>
__global__ __launch_bounds__(320, 3) void k_main(
    const float* __restrict__ data, const float* __restrict__ noise,
    const float* __restrict__ pmean, const float* __restrict__ plogv,
    float* __restrict__ ws, float* __restrict__ bigp) {
  __shared__ __align__(16) float dT[4096];
  __shared__ __align__(16) float zT[4096];

  const int t = threadIdx.x;
  const bool gram = (t < 256);
  const int w  = t >> 6;               // 0..4
  const int l  = t & 63;
  const int li = l >> 3, lj = l & 7;   // gram 8x8 lane tile
  const int q  = t & 15, rr = t >> 4;  // staging ids (gram only)
  const int chunk0 = blockIdx.x * (SUBT << 6);
  float* dst = ATOMIC ? ws : (bigp + (size_t)blockIdx.x * PSTRIDE);

  float acc[8][8];
#pragma unroll
  for (int a = 0; a < 8; ++a)
#pragma unroll
    for (int b = 0; b < 8; ++b) acc[a][b] = 0.0f;
  float z2p[4] = {0.f, 0.f, 0.f, 0.f};
  float eacc = 0.0f;

  float4 dv[4], zv[4];                 // gram prefetch regs

  const float* aT = (w < 2) ? zT : dT; // wave-uniform operand select
  const int kbase = (w & 1) << 5;

  auto LOAD = [&](int s) {
#pragma unroll
    for (int it = 0; it < 4; ++it) {
      const int r = rr + (it << 4);
      const size_t off = (size_t)r * DDIM + chunk0 + (s << 6) + (q << 2);
      dv[it] = *(const float4*)(data  + off);
      zv[it] = *(const float4*)(noise + off);
    }
  };
  auto WRITE = [&]() {
#pragma unroll
    for (int it = 0; it < 4; ++it) {
      const int r = rr + (it << 4);
      z2p[it] += zv[it].x * zv[it].x + zv[it].y * zv[it].y +
                 zv[it].z * zv[it].z + zv[it].w * zv[it].w;
      const int rq = r >> 2, rm = r & 3;
      const float* dp = (const float*)&dv[it];
      const float* zp = (const float*)&zv[it];
#pragma unroll
      for (int e = 0; e < 4; ++e) {
        const int k = (q << 2) + e;
        const int word = (k << 6) + ((rq ^ (k & 15)) << 2) + rm;
        dT[word] = dp[e];
        zT[word] = zp[e];
      }
    }
  };

  if (gram) { LOAD(0); WRITE(); }

  for (int s = 0; s < SUBT; ++s) {
    if (gram && s + 1 < SUBT) LOAD(s + 1);
    __syncthreads();                   // tile s writes visible
    if (gram) {
#pragma unroll 4
      for (int kk = 0; kk < 32; ++kk) {
        const int k   = kbase + kk;
        const int kb  = k << 6;
        const int sw2 = (k & 15) << 2;
        const float4 a0 = *(const float4*)(aT + kb + ((li << 3) ^ sw2));
        const float4 a1 = *(const float4*)(aT + kb + (((li << 3) | 4) ^ sw2));
        const float4 b0 = *(const float4*)(dT + kb + ((lj << 3) ^ sw2));
        const float4 b1 = *(const float4*)(dT + kb + (((lj << 3) | 4) ^ sw2));
        const float a8[8] = {a0.x, a0.y, a0.z, a0.w, a1.x, a1.y, a1.z, a1.w};
        const float b8[8] = {b0.x, b0.y, b0.z, b0.w, b1.x, b1.y, b1.z, b1.w};
#pragma unroll
        for (int ii = 0; ii < 8; ++ii)
#pragma unroll
          for (int jj = 0; jj < 8; ++jj)
            acc[ii][jj] = fmaf(a8[ii], b8[jj], acc[ii][jj]);
      }
    } else {
      // elem engine: this subtile's 64 rows x 64 k; lane covers (4i+er, ekq)
      const int er = l >> 4, ekq = l & 15;
      const int k0 = chunk0 + (s << 6);
      float4 cd, cz, cp, cg, nd, nz, np, ng;
      auto EL = [&](int i, float4& a, float4& b, float4& c, float4& d) {
        const size_t off = (size_t)((i << 2) + er) * DDIM + k0 + (ekq << 2);
        a = *(const float4*)(data  + off);
        b = *(const float4*)(noise + off);
        c = *(const float4*)(pmean + off);
        d = *(const float4*)(plogv + off);
      };
      EL(0, cd, cz, cp, cg);
#pragma unroll
      for (int i = 0; i < 16; ++i) {
        if (i + 1 < 16) EL(i + 1, nd, nz, np, ng);
        const float* dp = (const float*)&cd;
        const float* zp = (const float*)&cz;
        const float* pp = (const float*)&cp;
        const float* gp = (const float*)&cg;
#pragma unroll
        for (int e = 0; e < 4; ++e) {
          const float fc  = dp[e] - zp[e];
          const float dpm = pp[e] - fc;
          eacc += 0.5f * (dpm * dpm + __expf(gp[e]) * gp[e] - fc * fc);
        }
        cd = nd; cz = nz; cp = np; cg = ng;
      }
    }
    __syncthreads();                   // tile s reads done
    if (gram && s + 1 < SUBT) WRITE();
  }

  // ---- epilogue ----
  if (gram) {
    float* outT = (w < 2) ? zT : dT;   // ZD -> zT, DD -> dT
    if ((w & 1) == 0) {
#pragma unroll
      for (int ii = 0; ii < 8; ++ii)
#pragma unroll
        for (int h = 0; h < 2; ++h) {
          float4 v;
          v.x = acc[ii][h * 4 + 0]; v.y = acc[ii][h * 4 + 1];
          v.z = acc[ii][h * 4 + 2]; v.w = acc[ii][h * 4 + 3];
          *(float4*)(outT + (((li << 3) + ii) << 6) + (lj << 3) + (h << 2)) = v;
        }
    }
    // z2 row sums: rows rr+16it, reduce across 16 staging k-quad lanes
#pragma unroll
    for (int it = 0; it < 4; ++it) {
      float v = z2p[it];
      v += __shfl_xor(v, 1); v += __shfl_xor(v, 2);
      v += __shfl_xor(v, 4); v += __shfl_xor(v, 8);
      if ((l & 15) == 0) {
        if (ATOMIC) atomicAdd(ws + WS_Z2 + rr + (it << 4), v);
        else        dst[WS_Z2 + rr + (it << 4)] = v;
      }
    }
  } else {
    float ev = eacc;
#pragma unroll
    for (int m = 1; m <= 32; m <<= 1) ev += __shfl_xor(ev, m);
    if (l == 0) {
      if (ATOMIC) atomicAdd(ws + WS_ELEM, ev);
      else        dst[WS_ELEM] = ev;
    }
  }
  __syncthreads();                     // even-wave stores visible
  if (gram && (w & 1)) {
    float* outT = (w < 2) ? zT : dT;
#pragma unroll
    for (int ii = 0; ii < 8; ++ii)
#pragma unroll
      for (int h = 0; h < 2; ++h) {
        float* p = outT + (((li << 3) + ii) << 6) + (lj << 3) + (h << 2);
        float4 v = *(float4*)p;
        v.x += acc[ii][h * 4 + 0]; v.y += acc[ii][h * 4 + 1];
        v.z += acc[ii][h * 4 + 2]; v.w += acc[ii][h * 4 + 3];
        *(float4*)p = v;
      }
  }
  __syncthreads();                     // tiles final
  if (gram) {
    if (ATOMIC) {
#pragma unroll
      for (int e = 0; e < 16; ++e) {
        atomicAdd(ws + WS_ZD + (t << 4) + e, zT[(t << 4) + e]);
        atomicAdd(ws + WS_DD + (t << 4) + e, dT[(t << 4) + e]);
      }
    } else {
#pragma unroll
      for (int e = 0; e < 4; ++e) {
        *(float4*)(dst + WS_ZD + (t << 4) + (e << 2)) =
            *(const float4*)(zT + (t << 4) + (e << 2));
        *(float4*)(dst + WS_DD + (t << 4) + (e << 2)) =
            *(const float4*)(dT + (t << 4) + (e << 2));
      }
    }
  }
}

// Fold NB per-block partials into ws[0..NRED). 8-way atomic contention only.
__global__ void k_reduce(const float* __restrict__ bigp, float* __restrict__ ws,
                         int nb) {
  const int idx = blockIdx.x * 64 + threadIdx.x;
  if (idx >= NRED) return;
  const int per = nb >> 3;
  const size_t b0 = (size_t)blockIdx.y * per;
  float s = 0.f;
#pragma unroll 4
  for (int b = 0; b < per; ++b)
    s += bigp[(b0 + b) * PSTRIDE + idx];
  atomicAdd(ws + idx, s);
}

// ---------------------------------------------------------------------------
// k_small: per row i — reconstruct cross/d2/n2 from Grams, softmax, then
//   sum_k u^2 = (w^T DD w - 2 w.cross_i + n2_i) / (1 - t + eps)^2
//   cross_ij = (1-t) ZD[i][j] + t DD[i][j]
//   n2_i = (1-t)^2 z2_i + 2t(1-t) ZD[i][i] + t^2 DD[i][i]
// ---------------------------------------------------------------------------
__global__ void k_small(const float* __restrict__ times, float* __restrict__ ws) {
  const int i = blockIdx.x;
  const int j = threadIdx.x;
  const double tt = (double)(times[i] * T_SCALE);
  const double omt = 1.0 - tt;
  const double var = omt * omt + 1e-8;
  const double inv2v = 1.0 / (2.0 * var);
  const double zd = (double)ws[WS_ZD + (i << 6) + j];
  const double dd = (double)ws[WS_DD + (i << 6) + j];
  const double cross = omt * zd + tt * dd;
  const double d2j = (double)ws[WS_DD + j * 65];
  const double lg = (2.0 * tt * cross - tt * tt * d2j) * inv2v;
  double m = lg;
#pragma unroll
  for (int msk = 1; msk <= 32; msk <<= 1) m = fmax(m, __shfl_xor(m, msk));
  const double e = exp(lg - m);
  double S = e;
#pragma unroll
  for (int msk = 1; msk <= 32; msk <<= 1) S += __shfl_xor(S, msk);
  const double wgt = e / S;

  __shared__ double wsh[64];
  wsh[j] = wgt;
  __syncthreads();
  double inner = 0.0;
#pragma unroll 8
  for (int j2 = 0; j2 < 64; ++j2)
    inner += wsh[j2] * (double)ws[WS_DD + (j << 6) + j2];
  double s1 = wgt * inner;
  double s2 = wgt * cross;
#pragma unroll
  for (int msk = 1; msk <= 32; msk <<= 1) {
    s1 += __shfl_xor(s1, msk);
    s2 += __shfl_xor(s2, msk);
  }
  if (j == 0) {
    const double zdii = (double)ws[WS_ZD + i * 65];
    const double d2i  = (double)ws[WS_DD + i * 65];
    const double z2i  = (double)ws[WS_Z2 + i];
    const double n2   = omt * omt * z2i + 2.0 * tt * omt * zdii + tt * tt * d2i;
    const double den  = omt + 1e-8;
    ws[WS_U2 + i] = (float)((s1 - 2.0 * s2 + n2) / (den * den));
  }
}

__global__ void k_final(const float* __restrict__ ws, float* __restrict__ out) {
  const int t = threadIdx.x;
  double v = 0.5 * (double)ws[WS_U2 + t];
  if (t == 0) v += (double)ws[WS_ELEM];
#pragma unroll
  for (int m = 1; m <= 32; m <<= 1) v += __shfl_xor(v, m);
  if (t == 0) out[0] = (float)(v / (double)((size_t)BB * DDIM));
}

}  // namespace

extern "C" void kernel_launch(void* const* d_in, const int* in_sizes, int n_in,
                              void* d_out, int out_size, void* d_ws, size_t ws_size,
                              hipStream_t stream) {
  const float* data  = (const float*)d_in[0];
  const float* noise = (const float*)d_in[1];
  const float* times = (const float*)d_in[2];
  const float* pmean = (const float*)d_in[3];
  const float* plogv = (const float*)d_in[4];
  float* out = (float*)d_out;
  float* ws  = (float*)d_ws;
  float* bigp = ws + WS_BIGP;

  const bool fits512 =
      ws_size >= ((size_t)WS_BIGP + (size_t)512 * PSTRIDE) * sizeof(float);

  k_init<<<dim3(33), dim3(256), 0, stream>>>(ws);
  if (fits512) {
    k_main<6, false><<<dim3(512), dim3(320), 0, stream>>>(
        data, noise, pmean, plogv, ws, bigp);
    k_reduce<<<dim3(130, 8), dim3(64), 0, stream>>>(bigp, ws, 512);
  } else {
    k_main<6, true><<<dim3(512), dim3(320), 0, stream>>>(
        data, noise, pmean, plogv, ws, bigp);
  }
  k_small<<<dim3(64), dim3(64), 0, stream>>>(times, ws);
  k_final<<<dim3(1), dim3(64), 0, stream>>>(ws, out);
}

// Round 5
// 136.766 us; speedup vs baseline: 1.6812x; 1.6812x over previous
//
#include <hip/hip_runtime.h>

namespace {

constexpr int BB = 64;
constexpr int DDIM = 196608;          // 3*256*256
constexpr float T_SCALE = 0.99f;      // 1 - 1/MAX_TIMESTEPS

// ws layout (floats). Per-block partials in bigp mirror ws offsets for idx<NRED.
constexpr int WS_ZD   = 0;            // 64*64  ZD[i][j] = z_i . d_j
constexpr int WS_DD   = 4096;         // 64*64  DD[i][j] = d_i . d_j
constexpr int WS_Z2   = 8192;         // 64     |z_i|^2
constexpr int WS_ELEM = 8256;         // 1      elementwise loss total
constexpr int NRED    = 8257;
constexpr int WS_U2   = 8320;         // 64 per-row sum(u^2)
constexpr int WS_BIGP = 8384;
constexpr int PSTRIDE = 8272;         // per-block stride (16B aligned)

__global__ void k_init(float* __restrict__ ws) {
  int idx = blockIdx.x * 256 + threadIdx.x;
  if (idx < NRED) ws[idx] = 0.0f;
}

// ---------------------------------------------------------------------------
// k_main: dual Grams + z2 + fused elementwise loss. 512 threads / 8 waves.
//   ZD[i][j] = z_i . d_j,  DD[i][j] = d_i . d_j,  z2[i] = |z_i|^2
//   elem = sum 0.5*(pm^2 + exp(plv)*plv) - pm*(d - z)
//     (expansion of 0.5[(pm-fc)^2 + exp(plv)*plv - fc^2], fc = d-z)
// GEMM: each wave computes one FULL 64x64 gram over a 16-wide k-slice:
//   waves 0-3 -> ZD (k-parts 0..3), waves 4-7 -> DD. 8x8 acc per lane
//   (lane grid 8x8). Epilogue: 4-step in-LDS part reduction, stream to bigp.
// Staging: all 512 threads; thread t loads rows (t>>4) and (t>>4)+32 at
//   k-quad (t&15) for d,z (prefetched) + pm,plv (transient, elem only).
// LDS tiles k-major, quad XOR swizzle: word(k,r)=k*64+((r>>2)^(k&15))*4+(r&3);
//   b128 reads of row-octets are conflict-free broadcast8.
// ---------------------------------------------------------------------------
template <int SUBT, bool ATOMIC>
__global__ __launch_bounds__(512, 4) void k_main(
    const float* __restrict__ data, const float* __restrict__ noise,
    const float* __restrict__ pmean, const float* __restrict__ plogv,
    float* __restrict__ ws, float* __restrict__ bigp) {
  __shared__ __align__(16) float dT[4096];
  __shared__ __align__(16) float zT[4096];
  __shared__ float esm[8];

  const int t = threadIdx.x;
  const int w = t >> 6;                // 0..7
  const int l = t & 63;
  const int li = l >> 3, lj = l & 7;   // 8x8 lane grid
  const int q = t & 15, rr = t >> 5 == 0 ? (t >> 4) : (t >> 4); // rr = t>>4 (0..31)
  const int rbase = t >> 4;            // staging row 0..31 (plus +32)
  const int part = w & 3;
  const int kbase = part << 4;
  const float* aT = (w < 4) ? zT : dT; // wave-uniform operand select
  const int chunk0 = blockIdx.x * (SUBT << 6);
  float* dst = ATOMIC ? ws : (bigp + (size_t)blockIdx.x * PSTRIDE);

  float acc[8][8];
#pragma unroll
  for (int a = 0; a < 8; ++a)
#pragma unroll
    for (int b = 0; b < 8; ++b) acc[a][b] = 0.0f;
  float z2p[2] = {0.f, 0.f};
  float eacc = 0.0f;
  float4 dv[2], zv[2];

  auto LOAD = [&](int s) {
#pragma unroll
    for (int it = 0; it < 2; ++it) {
      const int r = rbase + (it << 5);
      const size_t off = (size_t)r * DDIM + chunk0 + (s << 6) + (q << 2);
      dv[it] = *(const float4*)(data  + off);
      zv[it] = *(const float4*)(noise + off);
    }
  };
  auto WRITE = [&](int s) {
#pragma unroll
    for (int it = 0; it < 2; ++it) {
      const int r = rbase + (it << 5);
      const size_t off = (size_t)r * DDIM + chunk0 + (s << 6) + (q << 2);
      const float4 pm4 = *(const float4*)(pmean + off);
      const float4 pl4 = *(const float4*)(plogv + off);
      z2p[it] += zv[it].x * zv[it].x + zv[it].y * zv[it].y +
                 zv[it].z * zv[it].z + zv[it].w * zv[it].w;
      const float* dp = (const float*)&dv[it];
      const float* zp = (const float*)&zv[it];
      const float* pp = (const float*)&pm4;
      const float* gp = (const float*)&pl4;
#pragma unroll
      for (int e = 0; e < 4; ++e) {
        const float fc = dp[e] - zp[e];
        eacc += 0.5f * (pp[e] * pp[e] + __expf(gp[e]) * gp[e]) - pp[e] * fc;
      }
      const int rq = r >> 2, rm = r & 3;
#pragma unroll
      for (int e = 0; e < 4; ++e) {
        const int k = (q << 2) + e;
        const int word = (k << 6) + ((rq ^ (k & 15)) << 2) + rm;
        dT[word] = dp[e];
        zT[word] = zp[e];
      }
    }
  };

  LOAD(0);
  WRITE(0);
  for (int s = 0; s < SUBT; ++s) {
    if (s + 1 < SUBT) LOAD(s + 1);
    __syncthreads();                   // tile s writes visible
#pragma unroll 4
    for (int kk = 0; kk < 16; ++kk) {
      const int k   = kbase + kk;
      const int kb  = k << 6;
      const int sw2 = (k & 15) << 2;
      const float4 a0 = *(const float4*)(aT + kb + ((li << 3) ^ sw2));
      const float4 a1 = *(const float4*)(aT + kb + (((li << 3) | 4) ^ sw2));
      const float4 b0 = *(const float4*)(dT + kb + ((lj << 3) ^ sw2));
      const float4 b1 = *(const float4*)(dT + kb + (((lj << 3) | 4) ^ sw2));
      const float a8[8] = {a0.x, a0.y, a0.z, a0.w, a1.x, a1.y, a1.z, a1.w};
      const float b8[8] = {b0.x, b0.y, b0.z, b0.w, b1.x, b1.y, b1.z, b1.w};
#pragma unroll
      for (int ii = 0; ii < 8; ++ii)
#pragma unroll
        for (int jj = 0; jj < 8; ++jj)
          acc[ii][jj] = fmaf(a8[ii], b8[jj], acc[ii][jj]);
    }
    __syncthreads();                   // tile s reads done
    if (s + 1 < SUBT) WRITE(s + 1);
  }

  // ---- z2 / elem reductions (no LDS-tile interaction) ----
#pragma unroll
  for (int it = 0; it < 2; ++it) {
    float v = z2p[it];
    v += __shfl_xor(v, 1); v += __shfl_xor(v, 2);
    v += __shfl_xor(v, 4); v += __shfl_xor(v, 8);
    if ((l & 15) == 0) {
      const int r = rbase + (it << 5);
      if (ATOMIC) atomicAdd(ws + WS_Z2 + r, v);
      else        dst[WS_Z2 + r] = v;
    }
  }
  {
    float ev = eacc;
#pragma unroll
    for (int m = 1; m <= 32; m <<= 1) ev += __shfl_xor(ev, m);
    if (l == 0) esm[w] = ev;
  }

  // ---- 4-step k-part reduction into zT (ZD) / dT (DD) ----
  float* outT = (w < 4) ? zT : dT;
#pragma unroll
  for (int p = 0; p < 4; ++p) {
    if (part == p) {
#pragma unroll
      for (int ii = 0; ii < 8; ++ii)
#pragma unroll
        for (int h = 0; h < 2; ++h) {
          float* ptr = outT + (((li << 3) + ii) << 6) + (lj << 3) + (h << 2);
          float4 v;
          v.x = acc[ii][h * 4 + 0]; v.y = acc[ii][h * 4 + 1];
          v.z = acc[ii][h * 4 + 2]; v.w = acc[ii][h * 4 + 3];
          if (p != 0) {
            const float4 o = *(const float4*)ptr;
            v.x += o.x; v.y += o.y; v.z += o.z; v.w += o.w;
          }
          *(float4*)ptr = v;
        }
    }
    __syncthreads();
  }

  // ---- stream per-block partials ----
  if (ATOMIC) {
#pragma unroll
    for (int e = 0; e < 8; ++e) {
      atomicAdd(ws + WS_ZD + (t << 3) + e, zT[(t << 3) + e]);
      atomicAdd(ws + WS_DD + (t << 3) + e, dT[(t << 3) + e]);
    }
    if (t == 0) {
      float s0 = 0.f;
#pragma unroll
      for (int e = 0; e < 8; ++e) s0 += esm[e];
      atomicAdd(ws + WS_ELEM, s0);
    }
  } else {
#pragma unroll
    for (int e = 0; e < 2; ++e) {
      *(float4*)(dst + WS_ZD + (t << 3) + (e << 2)) =
          *(const float4*)(zT + (t << 3) + (e << 2));
      *(float4*)(dst + WS_DD + (t << 3) + (e << 2)) =
          *(const float4*)(dT + (t << 3) + (e << 2));
    }
    if (t == 0) {
      float s0 = 0.f;
#pragma unroll
      for (int e = 0; e < 8; ++e) s0 += esm[e];
      dst[WS_ELEM] = s0;
    }
  }
}

// Fold NB per-block partials into ws[0..NRED). 8-way atomic contention only.
__global__ void k_reduce(const float* __restrict__ bigp, float* __restrict__ ws,
                         int nb) {
  const int idx = blockIdx.x * 64 + threadIdx.x;
  if (idx >= NRED) return;
  const int per = nb >> 3;
  const size_t b0 = (size_t)blockIdx.y * per;
  float s = 0.f;
#pragma unroll 4
  for (int b = 0; b < per; ++b)
    s += bigp[(b0 + b) * PSTRIDE + idx];
  atomicAdd(ws + idx, s);
}

// ---------------------------------------------------------------------------
// k_small: per row i — reconstruct cross/d2/n2 from Grams, softmax, then
//   sum_k u^2 = (w^T DD w - 2 w.cross_i + n2_i) / (1 - t + eps)^2
//   cross_ij = (1-t) ZD[i][j] + t DD[i][j]
//   n2_i = (1-t)^2 z2_i + 2t(1-t) ZD[i][i] + t^2 DD[i][i]
// ---------------------------------------------------------------------------
__global__ void k_small(const float* __restrict__ times, float* __restrict__ ws) {
  const int i = blockIdx.x;
  const int j = threadIdx.x;
  const double tt = (double)(times[i] * T_SCALE);
  const double omt = 1.0 - tt;
  const double var = omt * omt + 1e-8;
  const double inv2v = 1.0 / (2.0 * var);
  const double zd = (double)ws[WS_ZD + (i << 6) + j];
  const double dd = (double)ws[WS_DD + (i << 6) + j];
  const double cross = omt * zd + tt * dd;
  const double d2j = (double)ws[WS_DD + j * 65];
  const double lg = (2.0 * tt * cross - tt * tt * d2j) * inv2v;
  double m = lg;
#pragma unroll
  for (int msk = 1; msk <= 32; msk <<= 1) m = fmax(m, __shfl_xor(m, msk));
  const double e = exp(lg - m);
  double S = e;
#pragma unroll
  for (int msk = 1; msk <= 32; msk <<= 1) S += __shfl_xor(S, msk);
  const double wgt = e / S;

  __shared__ double wsh[64];
  wsh[j] = wgt;
  __syncthreads();
  double inner = 0.0;
#pragma unroll 8
  for (int j2 = 0; j2 < 64; ++j2)
    inner += wsh[j2] * (double)ws[WS_DD + (j << 6) + j2];
  double s1 = wgt * inner;
  double s2 = wgt * cross;
#pragma unroll
  for (int msk = 1; msk <= 32; msk <<= 1) {
    s1 += __shfl_xor(s1, msk);
    s2 += __shfl_xor(s2, msk);
  }
  if (j == 0) {
    const double zdii = (double)ws[WS_ZD + i * 65];
    const double d2i  = (double)ws[WS_DD + i * 65];
    const double z2i  = (double)ws[WS_Z2 + i];
    const double n2   = omt * omt * z2i + 2.0 * tt * omt * zdii + tt * tt * d2i;
    const double den  = omt + 1e-8;
    ws[WS_U2 + i] = (float)((s1 - 2.0 * s2 + n2) / (den * den));
  }
}

__global__ void k_final(const float* __restrict__ ws, float* __restrict__ out) {
  const int t = threadIdx.x;
  double v = 0.5 * (double)ws[WS_U2 + t];
  if (t == 0) v += (double)ws[WS_ELEM];
#pragma unroll
  for (int m = 1; m <= 32; m <<= 1) v += __shfl_xor(v, m);
  if (t == 0) out[0] = (float)(v / (double)((size_t)BB * DDIM));
}

}  // namespace

extern "C" void kernel_launch(void* const* d_in, const int* in_sizes, int n_in,
                              void* d_out, int out_size, void* d_ws, size_t ws_size,
                              hipStream_t stream) {
  const float* data  = (const float*)d_in[0];
  const float* noise = (const float*)d_in[1];
  const float* times = (const float*)d_in[2];
  const float* pmean = (const float*)d_in[3];
  const float* plogv = (const float*)d_in[4];
  float* out = (float*)d_out;
  float* ws  = (float*)d_ws;
  float* bigp = ws + WS_BIGP;

  const bool fits512 =
      ws_size >= ((size_t)WS_BIGP + (size_t)512 * PSTRIDE) * sizeof(float);

  k_init<<<dim3(33), dim3(256), 0, stream>>>(ws);
  if (fits512) {
    k_main<6, false><<<dim3(512), dim3(512), 0, stream>>>(
        data, noise, pmean, plogv, ws, bigp);
    k_reduce<<<dim3(130, 8), dim3(64), 0, stream>>>(bigp, ws, 512);
  } else {
    k_main<6, true><<<dim3(512), dim3(512), 0, stream>>>(
        data, noise, pmean, plogv, ws, bigp);
  }
  k_small<<<dim3(64), dim3(64), 0, stream>>>(times, ws);
  k_final<<<dim3(1), dim3(64), 0, stream>>>(ws, out);
}